// Round 1
// baseline (985.340 us; speedup 1.0000x reference)
//
#include <hip/hip_runtime.h>
#include <math.h>

#define TB 16
#define TT 4096
#define TE 512
#define NF 2049   // rfft bins
#define TOPK 16

// ---------- helpers ----------
__device__ __forceinline__ int dr4(int u) {
  // reverse 6 base-4 digits (12 bits)
  return ((u & 3) << 10) | (((u >> 2) & 3) << 8) | (((u >> 4) & 3) << 6) |
         (((u >> 6) & 3) << 4) | (((u >> 8) & 3) << 2) | ((u >> 10) & 3);
}
__device__ __forceinline__ int swz(int i) { return i ^ (i >> 4); }  // LDS bank de-conflict, bijective on [0,4096)
__device__ __forceinline__ float2 cmul(float2 a, float2 b) {
  return make_float2(a.x * b.x - a.y * b.y, a.x * b.y + a.y * b.x);
}

// ---------- K1: per-channel FFT (z = q + i k), accumulate S[b,f] = sum_e Qf*conj(Kf) ----------
extern "C" __global__ void __launch_bounds__(512)
k1_spec(const float* __restrict__ Qg, const float* __restrict__ Kg, float* __restrict__ S) {
  __shared__ float2 z[4][4096];   // 128 KiB
  __shared__ float2 tw[1024];     // e^{-2pi i k/4096}, 8 KiB
  const int tid = threadIdx.x;
  const int b   = blockIdx.x >> 4;
  const int grp = blockIdx.x & 15;

  for (int k = tid; k < 1024; k += 512) {
    float s, c;
    sincosf(-6.283185307179586f * (float)k / 4096.0f, &s, &c);
    tw[k] = make_float2(c, s);
  }

  float accr[5] = {0, 0, 0, 0, 0};
  float acci[5] = {0, 0, 0, 0, 0};
  const size_t base = (size_t)b * TT * TE;
  const int ch = tid >> 7;   // 128 lanes (2 waves) per channel FFT
  const int l  = tid & 127;

  for (int it = 0; it < 8; ++it) {
    const int e0 = grp * 32 + it * 4;
    __syncthreads();  // protect z reuse (and tw on first iter)
    // load 4 channels: z[c][t] = (Q, K)
    for (int j = 0; j < 8; ++j) {
      const int t = tid + 512 * j;
      const float4 q4 = *(const float4*)(Qg + base + (size_t)t * TE + e0);
      const float4 k4 = *(const float4*)(Kg + base + (size_t)t * TE + e0);
      const int p = swz(t);
      z[0][p] = make_float2(q4.x, k4.x);
      z[1][p] = make_float2(q4.y, k4.y);
      z[2][p] = make_float2(q4.z, k4.z);
      z[3][p] = make_float2(q4.w, k4.w);
    }
    __syncthreads();

    // 6-stage in-place radix-4 DIF (natural in -> digit-reversed out)
    float2* zz = z[ch];
#pragma unroll
    for (int s = 0; s < 6; ++s) {
      const int M  = 4096 >> (2 * s);
      const int Qq = M >> 2;
      const int LQ = 10 - 2 * s;
      for (int q = 0; q < 8; ++q) {
        const int v    = l + 128 * q;         // 0..1023 butterflies
        const int blk  = v >> LQ;
        const int j    = v & (Qq - 1);
        const int bse  = blk * M + j;
        float2 a0 = zz[swz(bse)];
        float2 a1 = zz[swz(bse + Qq)];
        float2 a2 = zz[swz(bse + 2 * Qq)];
        float2 a3 = zz[swz(bse + 3 * Qq)];
        float2 t0 = {a0.x + a2.x, a0.y + a2.y};
        float2 t1 = {a0.x - a2.x, a0.y - a2.y};
        float2 t2 = {a1.x + a3.x, a1.y + a3.y};
        float2 t3 = {a1.x - a3.x, a1.y - a3.y};
        float2 u0 = {t0.x + t2.x, t0.y + t2.y};
        float2 u2 = {t0.x - t2.x, t0.y - t2.y};
        float2 u1 = {t1.x + t3.y, t1.y - t3.x};  // t1 - i t3
        float2 u3 = {t1.x - t3.y, t1.y + t3.x};  // t1 + i t3
        const float2 w1 = tw[j << (2 * s)];
        const float2 w2 = cmul(w1, w1);
        const float2 w3 = cmul(w1, w2);
        zz[swz(bse)]          = u0;
        zz[swz(bse + Qq)]     = cmul(u1, w1);
        zz[swz(bse + 2 * Qq)] = cmul(u2, w2);
        zz[swz(bse + 3 * Qq)] = cmul(u3, w3);
      }
      __syncthreads();
    }

    // unpack q+ik, P = Qf*conj(Kf), accumulate (digit-reversed gather -> natural f)
#pragma unroll
    for (int r = 0; r < 5; ++r) {
      const int f = tid + 512 * r;
      if (f <= 2048) {
        const int u  = swz(dr4(f));
        const int u2 = swz(dr4((4096 - f) & 4095));
#pragma unroll
        for (int c = 0; c < 4; ++c) {
          const float2 Zf = z[c][u];
          float2 Zc = z[c][u2];
          Zc.y = -Zc.y;  // conj(Z[N-f])
          const float qx = 0.5f * (Zf.x + Zc.x), qy = 0.5f * (Zf.y + Zc.y);
          const float dx = Zf.x - Zc.x,          dy = Zf.y - Zc.y;
          const float kx = 0.5f * dy,            ky = -0.5f * dx;  // Kf = -i/2 * (Zf - Zc)
          accr[r] += qx * kx + qy * ky;   // Re(Qf * conj(Kf))
          acci[r] += qy * kx - qx * ky;   // Im(Qf * conj(Kf))
        }
      }
    }
  }

#pragma unroll
  for (int r = 0; r < 5; ++r) {
    const int f = tid + 512 * r;
    if (f <= 2048) {
      atomicAdd(S + ((size_t)b * NF + f) * 2 + 0, accr[r]);
      atomicAdd(S + ((size_t)b * NF + f) * 2 + 1, acci[r]);
    }
  }
}

// ---------- K2: inverse FFT of S -> mean_corr (scale 1/(N*E)) ----------
extern "C" __global__ void __launch_bounds__(512)
k2_irfft(const float* __restrict__ S, float* __restrict__ mc) {
  __shared__ float2 z[4096];
  __shared__ float2 tw[1024];  // e^{+2pi i k/4096}
  const int tid = threadIdx.x;
  const int b   = blockIdx.x;
  for (int k = tid; k < 1024; k += 512) {
    float s, c;
    sincosf(6.283185307179586f * (float)k / 4096.0f, &s, &c);
    tw[k] = make_float2(c, s);
  }
  __syncthreads();
  const float scale = 1.0f / (4096.0f * 512.0f);
  for (int jj = 0; jj < 8; ++jj) {
    const int u = tid + 512 * jj;
    const int f = dr4(u);
    float2 v;
    if (f <= 2048) {
      v = make_float2(S[((size_t)b * NF + f) * 2], S[((size_t)b * NF + f) * 2 + 1]);
    } else {
      const int f2 = 4096 - f;
      v = make_float2(S[((size_t)b * NF + f2) * 2], -S[((size_t)b * NF + f2) * 2 + 1]);
    }
    z[swz(u)] = make_float2(v.x * scale, v.y * scale);
  }
  __syncthreads();
  // radix-4 DIT, digit-reversed in -> natural out, +i convention
#pragma unroll
  for (int s = 5; s >= 0; --s) {
    const int M  = 4096 >> (2 * s);
    const int Qq = M >> 2;
    const int LQ = 10 - 2 * s;
    for (int q = 0; q < 2; ++q) {
      const int v   = tid + 512 * q;
      const int blk = v >> LQ;
      const int j   = v & (Qq - 1);
      const int bse = blk * M + j;
      float2 b0 = z[swz(bse)];
      float2 b1 = z[swz(bse + Qq)];
      float2 b2 = z[swz(bse + 2 * Qq)];
      float2 b3 = z[swz(bse + 3 * Qq)];
      const float2 w1 = tw[j << (2 * s)];
      const float2 w2 = cmul(w1, w1);
      const float2 w3 = cmul(w1, w2);
      b1 = cmul(b1, w1); b2 = cmul(b2, w2); b3 = cmul(b3, w3);
      float2 t0 = {b0.x + b2.x, b0.y + b2.y};
      float2 t1 = {b0.x - b2.x, b0.y - b2.y};
      float2 t2 = {b1.x + b3.x, b1.y + b3.y};
      float2 t3 = {b1.x - b3.x, b1.y - b3.y};
      z[swz(bse)]          = make_float2(t0.x + t2.x, t0.y + t2.y);
      z[swz(bse + Qq)]     = make_float2(t1.x - t3.y, t1.y + t3.x);  // t1 + i t3
      z[swz(bse + 2 * Qq)] = make_float2(t0.x - t2.x, t0.y - t2.y);
      z[swz(bse + 3 * Qq)] = make_float2(t1.x + t3.y, t1.y - t3.x);  // t1 - i t3
    }
    __syncthreads();
  }
  for (int jj = 0; jj < 8; ++jj) {
    const int t = tid + 512 * jj;
    mc[(size_t)b * TT + t] = z[swz(t)].x;
  }
}

// ---------- K3: global mean over b, top-16 delays, softmax weights ----------
extern "C" __global__ void __launch_bounds__(512)
k3_select(const float* __restrict__ mc, int* __restrict__ delays, float* __restrict__ wts) {
  __shared__ float gm[4096];
  __shared__ float red[512];
  __shared__ int   redi[512];
  __shared__ int   sel[TOPK];
  const int tid = threadIdx.x;
  for (int jj = 0; jj < 8; ++jj) {
    const int t = tid + 512 * jj;
    float ssum = 0.f;
    for (int b = 0; b < TB; ++b) ssum += mc[(size_t)b * TT + t];
    gm[t] = ssum;  // argmax of sum == argmax of mean
  }
  __syncthreads();
  for (int k = 0; k < TOPK; ++k) {
    float best = -3.0e38f; int bi = 0x7fffffff;
    for (int jj = 0; jj < 8; ++jj) {
      const int t = tid + 512 * jj;
      const float v = gm[t];
      if (v > best || (v == best && t < bi)) { best = v; bi = t; }
    }
    red[tid] = best; redi[tid] = bi;
    __syncthreads();
    for (int s = 256; s > 0; s >>= 1) {
      if (tid < s) {
        if (red[tid + s] > red[tid] ||
            (red[tid + s] == red[tid] && redi[tid + s] < redi[tid])) {
          red[tid] = red[tid + s]; redi[tid] = redi[tid + s];
        }
      }
      __syncthreads();
    }
    if (tid == 0) { sel[k] = redi[0]; gm[redi[0]] = -3.0e38f; }
    __syncthreads();
  }
  if (tid < TOPK) delays[tid] = sel[tid];
  if (tid < TB * TOPK) {
    const int b = tid >> 4, k = tid & 15;
    const float v = mc[(size_t)b * TT + sel[k]];
    float m = v;
    for (int o = 8; o > 0; o >>= 1) m = fmaxf(m, __shfl_xor(m, o, 16));
    const float e = expf(v - m);
    float ssum = e;
    for (int o = 8; o > 0; o >>= 1) ssum += __shfl_xor(ssum, o, 16);
    wts[tid] = e / ssum;  // wts[b*16+k]
  }
}

// ---------- K4: out[b,t,:] = sum_k w[b,k] * V[b,(t+d_k)%T,:] ----------
extern "C" __global__ void __launch_bounds__(256)
k4_out(const float* __restrict__ V, const int* __restrict__ delays,
       const float* __restrict__ wts, float* __restrict__ out) {
  __shared__ int   d_s[TOPK];
  __shared__ float w_s[TOPK];
  const int b  = blockIdx.x / (TT / 8);
  const int t0 = (blockIdx.x % (TT / 8)) * 8;
  const int tid = threadIdx.x;
  if (tid < TOPK) { d_s[tid] = delays[tid]; w_s[tid] = wts[b * TOPK + tid]; }
  __syncthreads();
  const int rowp = tid >> 7;       // 0..1
  const int e4   = tid & 127;      // float4 slot within a 512-float row
  const float* Vb = V   + (size_t)b * TT * TE;
  float*       Ob = out + (size_t)b * TT * TE;
  for (int p = 0; p < 4; ++p) {
    const int t = t0 + p * 2 + rowp;
    float4 acc = {0.f, 0.f, 0.f, 0.f};
#pragma unroll
    for (int k = 0; k < TOPK; ++k) {
      const int ts = (t + d_s[k]) & (TT - 1);
      const float4 v = *(const float4*)(Vb + (size_t)ts * TE + e4 * 4);
      const float w = w_s[k];
      acc.x += w * v.x; acc.y += w * v.y; acc.z += w * v.z; acc.w += w * v.w;
    }
    *(float4*)(Ob + (size_t)t * TE + e4 * 4) = acc;
  }
}

// ---------- launch ----------
extern "C" void kernel_launch(void* const* d_in, const int* in_sizes, int n_in,
                              void* d_out, int out_size, void* d_ws, size_t ws_size,
                              hipStream_t stream) {
  const float* Q = (const float*)d_in[0];
  const float* K = (const float*)d_in[1];
  const float* V = (const float*)d_in[2];
  float* out = (float*)d_out;

  // workspace layout (floats): S[16*2049*2] | mc[16*4096] | delays[16 ints] | wts[16*16]
  float* S      = (float*)d_ws;
  float* mc     = S + (size_t)TB * NF * 2;
  int*   delays = (int*)(mc + (size_t)TB * TT);
  float* wts    = (float*)(delays + TOPK);

  hipMemsetAsync(S, 0, (size_t)TB * NF * 2 * sizeof(float), stream);
  k1_spec<<<TB * 16, 512, 0, stream>>>(Q, K, S);
  k2_irfft<<<TB, 512, 0, stream>>>(S, mc);
  k3_select<<<1, 512, 0, stream>>>(mc, delays, wts);
  k4_out<<<TB * (TT / 8), 256, 0, stream>>>(V, delays, wts, out);
}

// Round 3
// 817.792 us; speedup vs baseline: 1.2049x; 1.2049x over previous
//
#include <hip/hip_runtime.h>
#include <math.h>

#define TB 16
#define TT 4096
#define TE 512
#define NF 2049   // rfft bins
#define TOPK 16

// ---------- helpers ----------
__device__ __forceinline__ int dr4(int u) {
  // reverse 6 base-4 digits (12 bits)
  return ((u & 3) << 10) | (((u >> 2) & 3) << 8) | (((u >> 4) & 3) << 6) |
         (((u >> 6) & 3) << 4) | (((u >> 8) & 3) << 2) | ((u >> 10) & 3);
}
__device__ __forceinline__ int swz(int i) { return i ^ (i >> 4); }  // LDS bank de-conflict, bijective on [0,4096)
__device__ __forceinline__ float2 cmul(float2 a, float2 b) {
  return make_float2(a.x * b.x - a.y * b.y, a.x * b.y + a.y * b.x);
}

// ---------- K0: transpose Q[b,t,e] -> Qt[b,e,t] (into d_out) and K -> Kt (into ws) ----------
extern "C" __global__ void __launch_bounds__(256)
k0_transpose(const float* __restrict__ Q, const float* __restrict__ K,
             float* __restrict__ Qt, float* __restrict__ Kt) {
  __shared__ float tile[64][65];
  const int tid = threadIdx.x;
  const int bid = blockIdx.x;          // 16 b * 64 ttiles * 8 etiles = 8192
  const int b   = bid >> 9;
  const int rem = bid & 511;
  const int t0  = (rem >> 3) * 64;
  const int e0  = (rem & 7) * 64;
  const size_t inb  = (size_t)b * TT * TE;
  const size_t outb = (size_t)b * TE * TT;
  const int r0 = tid >> 4;        // 0..15
  const int c0 = (tid & 15) * 4;  // 0..60

  // ---- Q ----
#pragma unroll
  for (int rr = 0; rr < 4; ++rr) {
    const int r = r0 + 16 * rr;
    const float4 v = *(const float4*)(Q + inb + (size_t)(t0 + r) * TE + e0 + c0);
    tile[r][c0] = v.x; tile[r][c0 + 1] = v.y; tile[r][c0 + 2] = v.z; tile[r][c0 + 3] = v.w;
  }
  __syncthreads();
#pragma unroll
  for (int rr = 0; rr < 4; ++rr) {
    const int er = r0 + 16 * rr;
    float4 w;
    w.x = tile[c0][er]; w.y = tile[c0 + 1][er]; w.z = tile[c0 + 2][er]; w.w = tile[c0 + 3][er];
    *(float4*)(Qt + outb + (size_t)(e0 + er) * TT + t0 + c0) = w;
  }
  __syncthreads();
  // ---- K ----
#pragma unroll
  for (int rr = 0; rr < 4; ++rr) {
    const int r = r0 + 16 * rr;
    const float4 v = *(const float4*)(K + inb + (size_t)(t0 + r) * TE + e0 + c0);
    tile[r][c0] = v.x; tile[r][c0 + 1] = v.y; tile[r][c0 + 2] = v.z; tile[r][c0 + 3] = v.w;
  }
  __syncthreads();
#pragma unroll
  for (int rr = 0; rr < 4; ++rr) {
    const int er = r0 + 16 * rr;
    float4 w;
    w.x = tile[c0][er]; w.y = tile[c0 + 1][er]; w.z = tile[c0 + 2][er]; w.w = tile[c0 + 3][er];
    *(float4*)(Kt + outb + (size_t)(e0 + er) * TT + t0 + c0) = w;
  }
}

// ---------- K1-fast: FFT from transposed layout (coalesced), accumulate S ----------
extern "C" __global__ void __launch_bounds__(512)
k1_fast(const float* __restrict__ Qt, const float* __restrict__ Kt, float* __restrict__ S) {
  __shared__ float2 z[4][4096];   // 128 KiB
  __shared__ float2 tw[1024];     // 8 KiB
  const int tid = threadIdx.x;
  const int b   = blockIdx.x >> 4;
  const int grp = blockIdx.x & 15;

  for (int k = tid; k < 1024; k += 512) {
    float s, c;
    sincosf(-6.283185307179586f * (float)k / 4096.0f, &s, &c);
    tw[k] = make_float2(c, s);
  }

  float accr[5] = {0, 0, 0, 0, 0};
  float acci[5] = {0, 0, 0, 0, 0};
  const int ch = tid >> 7;   // 0..3 : channel within quad
  const int l  = tid & 127;

  for (int it = 0; it < 8; ++it) {
    const int e0 = grp * 32 + it * 4;
    __syncthreads();  // protect z reuse (and tw on first iter)
    // coalesced load: each 128-lane group streams one 16-KB channel row
    const float* qrow = Qt + ((size_t)b * TE + e0 + ch) * TT;
    const float* krow = Kt + ((size_t)b * TE + e0 + ch) * TT;
#pragma unroll
    for (int j = 0; j < 8; ++j) {
      const int t4 = l + 128 * j;          // float4 index
      const float4 q4 = *(const float4*)(qrow + 4 * t4);
      const float4 k4 = *(const float4*)(krow + 4 * t4);
      const int t = 4 * t4;
      z[ch][swz(t + 0)] = make_float2(q4.x, k4.x);
      z[ch][swz(t + 1)] = make_float2(q4.y, k4.y);
      z[ch][swz(t + 2)] = make_float2(q4.z, k4.z);
      z[ch][swz(t + 3)] = make_float2(q4.w, k4.w);
    }
    __syncthreads();

    // 6-stage in-place radix-4 DIF (natural in -> digit-reversed out)
    float2* zz = z[ch];
#pragma unroll
    for (int s = 0; s < 6; ++s) {
      const int M  = 4096 >> (2 * s);
      const int Qq = M >> 2;
      const int LQ = 10 - 2 * s;
      for (int q = 0; q < 8; ++q) {
        const int v    = l + 128 * q;
        const int blk  = v >> LQ;
        const int j    = v & (Qq - 1);
        const int bse  = blk * M + j;
        float2 a0 = zz[swz(bse)];
        float2 a1 = zz[swz(bse + Qq)];
        float2 a2 = zz[swz(bse + 2 * Qq)];
        float2 a3 = zz[swz(bse + 3 * Qq)];
        float2 t0 = {a0.x + a2.x, a0.y + a2.y};
        float2 t1 = {a0.x - a2.x, a0.y - a2.y};
        float2 t2 = {a1.x + a3.x, a1.y + a3.y};
        float2 t3 = {a1.x - a3.x, a1.y - a3.y};
        float2 u0 = {t0.x + t2.x, t0.y + t2.y};
        float2 u2 = {t0.x - t2.x, t0.y - t2.y};
        float2 u1 = {t1.x + t3.y, t1.y - t3.x};  // t1 - i t3
        float2 u3 = {t1.x - t3.y, t1.y + t3.x};  // t1 + i t3
        const float2 w1 = tw[j << (2 * s)];
        const float2 w2 = cmul(w1, w1);
        const float2 w3 = cmul(w1, w2);
        zz[swz(bse)]          = u0;
        zz[swz(bse + Qq)]     = cmul(u1, w1);
        zz[swz(bse + 2 * Qq)] = cmul(u2, w2);
        zz[swz(bse + 3 * Qq)] = cmul(u3, w3);
      }
      __syncthreads();
    }

    // unpack q+ik, P = Qf*conj(Kf), accumulate
#pragma unroll
    for (int r = 0; r < 5; ++r) {
      const int f = tid + 512 * r;
      if (f <= 2048) {
        const int u  = swz(dr4(f));
        const int u2 = swz(dr4((4096 - f) & 4095));
#pragma unroll
        for (int c = 0; c < 4; ++c) {
          const float2 Zf = z[c][u];
          float2 Zc = z[c][u2];
          Zc.y = -Zc.y;
          const float qx = 0.5f * (Zf.x + Zc.x), qy = 0.5f * (Zf.y + Zc.y);
          const float dx = Zf.x - Zc.x,          dy = Zf.y - Zc.y;
          const float kx = 0.5f * dy,            ky = -0.5f * dx;
          accr[r] += qx * kx + qy * ky;
          acci[r] += qy * kx - qx * ky;
        }
      }
    }
  }

#pragma unroll
  for (int r = 0; r < 5; ++r) {
    const int f = tid + 512 * r;
    if (f <= 2048) {
      atomicAdd(S + ((size_t)b * NF + f) * 2 + 0, accr[r]);
      atomicAdd(S + ((size_t)b * NF + f) * 2 + 1, acci[r]);
    }
  }
}

// ---------- K1 legacy (fallback when ws too small): direct strided loads ----------
extern "C" __global__ void __launch_bounds__(512)
k1_spec(const float* __restrict__ Qg, const float* __restrict__ Kg, float* __restrict__ S) {
  __shared__ float2 z[4][4096];
  __shared__ float2 tw[1024];
  const int tid = threadIdx.x;
  const int b   = blockIdx.x >> 4;
  const int grp = blockIdx.x & 15;

  for (int k = tid; k < 1024; k += 512) {
    float s, c;
    sincosf(-6.283185307179586f * (float)k / 4096.0f, &s, &c);
    tw[k] = make_float2(c, s);
  }

  float accr[5] = {0, 0, 0, 0, 0};
  float acci[5] = {0, 0, 0, 0, 0};
  const size_t base = (size_t)b * TT * TE;
  const int ch = tid >> 7;
  const int l  = tid & 127;

  for (int it = 0; it < 8; ++it) {
    const int e0 = grp * 32 + it * 4;
    __syncthreads();
    for (int j = 0; j < 8; ++j) {
      const int t = tid + 512 * j;
      const float4 q4 = *(const float4*)(Qg + base + (size_t)t * TE + e0);
      const float4 k4 = *(const float4*)(Kg + base + (size_t)t * TE + e0);
      const int p = swz(t);
      z[0][p] = make_float2(q4.x, k4.x);
      z[1][p] = make_float2(q4.y, k4.y);
      z[2][p] = make_float2(q4.z, k4.z);
      z[3][p] = make_float2(q4.w, k4.w);
    }
    __syncthreads();

    float2* zz = z[ch];
#pragma unroll
    for (int s = 0; s < 6; ++s) {
      const int M  = 4096 >> (2 * s);
      const int Qq = M >> 2;
      const int LQ = 10 - 2 * s;
      for (int q = 0; q < 8; ++q) {
        const int v    = l + 128 * q;
        const int blk  = v >> LQ;
        const int j    = v & (Qq - 1);
        const int bse  = blk * M + j;
        float2 a0 = zz[swz(bse)];
        float2 a1 = zz[swz(bse + Qq)];
        float2 a2 = zz[swz(bse + 2 * Qq)];
        float2 a3 = zz[swz(bse + 3 * Qq)];
        float2 t0 = {a0.x + a2.x, a0.y + a2.y};
        float2 t1 = {a0.x - a2.x, a0.y - a2.y};
        float2 t2 = {a1.x + a3.x, a1.y + a3.y};
        float2 t3 = {a1.x - a3.x, a1.y - a3.y};
        float2 u0 = {t0.x + t2.x, t0.y + t2.y};
        float2 u2 = {t0.x - t2.x, t0.y - t2.y};
        float2 u1 = {t1.x + t3.y, t1.y - t3.x};
        float2 u3 = {t1.x - t3.y, t1.y + t3.x};
        const float2 w1 = tw[j << (2 * s)];
        const float2 w2 = cmul(w1, w1);
        const float2 w3 = cmul(w1, w2);
        zz[swz(bse)]          = u0;
        zz[swz(bse + Qq)]     = cmul(u1, w1);
        zz[swz(bse + 2 * Qq)] = cmul(u2, w2);
        zz[swz(bse + 3 * Qq)] = cmul(u3, w3);
      }
      __syncthreads();
    }

#pragma unroll
    for (int r = 0; r < 5; ++r) {
      const int f = tid + 512 * r;
      if (f <= 2048) {
        const int u  = swz(dr4(f));
        const int u2 = swz(dr4((4096 - f) & 4095));
#pragma unroll
        for (int c = 0; c < 4; ++c) {
          const float2 Zf = z[c][u];
          float2 Zc = z[c][u2];
          Zc.y = -Zc.y;
          const float qx = 0.5f * (Zf.x + Zc.x), qy = 0.5f * (Zf.y + Zc.y);
          const float dx = Zf.x - Zc.x,          dy = Zf.y - Zc.y;
          const float kx = 0.5f * dy,            ky = -0.5f * dx;
          accr[r] += qx * kx + qy * ky;
          acci[r] += qy * kx - qx * ky;
        }
      }
    }
  }

#pragma unroll
  for (int r = 0; r < 5; ++r) {
    const int f = tid + 512 * r;
    if (f <= 2048) {
      atomicAdd(S + ((size_t)b * NF + f) * 2 + 0, accr[r]);
      atomicAdd(S + ((size_t)b * NF + f) * 2 + 1, acci[r]);
    }
  }
}

// ---------- K2: inverse FFT of S -> mean_corr ----------
extern "C" __global__ void __launch_bounds__(512)
k2_irfft(const float* __restrict__ S, float* __restrict__ mc) {
  __shared__ float2 z[4096];
  __shared__ float2 tw[1024];
  const int tid = threadIdx.x;
  const int b   = blockIdx.x;
  for (int k = tid; k < 1024; k += 512) {
    float s, c;
    sincosf(6.283185307179586f * (float)k / 4096.0f, &s, &c);
    tw[k] = make_float2(c, s);
  }
  __syncthreads();
  const float scale = 1.0f / (4096.0f * 512.0f);
  for (int jj = 0; jj < 8; ++jj) {
    const int u = tid + 512 * jj;
    const int f = dr4(u);
    float2 v;
    if (f <= 2048) {
      v = make_float2(S[((size_t)b * NF + f) * 2], S[((size_t)b * NF + f) * 2 + 1]);
    } else {
      const int f2 = 4096 - f;
      v = make_float2(S[((size_t)b * NF + f2) * 2], -S[((size_t)b * NF + f2) * 2 + 1]);
    }
    z[swz(u)] = make_float2(v.x * scale, v.y * scale);
  }
  __syncthreads();
#pragma unroll
  for (int s = 5; s >= 0; --s) {
    const int M  = 4096 >> (2 * s);
    const int Qq = M >> 2;
    const int LQ = 10 - 2 * s;
    for (int q = 0; q < 2; ++q) {
      const int v   = tid + 512 * q;
      const int blk = v >> LQ;
      const int j   = v & (Qq - 1);
      const int bse = blk * M + j;
      float2 b0 = z[swz(bse)];
      float2 b1 = z[swz(bse + Qq)];
      float2 b2 = z[swz(bse + 2 * Qq)];
      float2 b3 = z[swz(bse + 3 * Qq)];
      const float2 w1 = tw[j << (2 * s)];
      const float2 w2 = cmul(w1, w1);
      const float2 w3 = cmul(w1, w2);
      b1 = cmul(b1, w1); b2 = cmul(b2, w2); b3 = cmul(b3, w3);
      float2 t0 = {b0.x + b2.x, b0.y + b2.y};
      float2 t1 = {b0.x - b2.x, b0.y - b2.y};
      float2 t2 = {b1.x + b3.x, b1.y + b3.y};
      float2 t3 = {b1.x - b3.x, b1.y - b3.y};
      z[swz(bse)]          = make_float2(t0.x + t2.x, t0.y + t2.y);
      z[swz(bse + Qq)]     = make_float2(t1.x - t3.y, t1.y + t3.x);
      z[swz(bse + 2 * Qq)] = make_float2(t0.x - t2.x, t0.y - t2.y);
      z[swz(bse + 3 * Qq)] = make_float2(t1.x + t3.y, t1.y - t3.x);
    }
    __syncthreads();
  }
  for (int jj = 0; jj < 8; ++jj) {
    const int t = tid + 512 * jj;
    mc[(size_t)b * TT + t] = z[swz(t)].x;
  }
}

// ---------- K3: global mean over b, top-16 delays, softmax weights (shfl reductions) ----------
extern "C" __global__ void __launch_bounds__(512)
k3_select(const float* __restrict__ mc, int* __restrict__ delays, float* __restrict__ wts) {
  __shared__ float gm[4096];
  __shared__ float redv[8];
  __shared__ int   redi[8];
  __shared__ int   sel[TOPK];
  const int tid  = threadIdx.x;
  const int lane = tid & 63;
  const int wv   = tid >> 6;
  for (int jj = 0; jj < 8; ++jj) {
    const int t = tid + 512 * jj;
    float ssum = 0.f;
    for (int b = 0; b < TB; ++b) ssum += mc[(size_t)b * TT + t];
    gm[t] = ssum;
  }
  __syncthreads();
  for (int k = 0; k < TOPK; ++k) {
    float best = -3.0e38f; int bi = 0x7fffffff;
#pragma unroll
    for (int jj = 0; jj < 8; ++jj) {
      const int t = tid + 512 * jj;
      const float v = gm[t];
      if (v > best || (v == best && t < bi)) { best = v; bi = t; }
    }
#pragma unroll
    for (int o = 32; o > 0; o >>= 1) {
      const float ov = __shfl_xor(best, o);
      const int   oi = __shfl_xor(bi, o);
      if (ov > best || (ov == best && oi < bi)) { best = ov; bi = oi; }
    }
    if (lane == 0) { redv[wv] = best; redi[wv] = bi; }
    __syncthreads();
    if (tid == 0) {
      float bb = redv[0]; int ii = redi[0];
      for (int w = 1; w < 8; ++w)
        if (redv[w] > bb || (redv[w] == bb && redi[w] < ii)) { bb = redv[w]; ii = redi[w]; }
      sel[k] = ii; gm[ii] = -3.0e38f;
    }
    __syncthreads();
  }
  if (tid < TOPK) delays[tid] = sel[tid];
  if (tid < TB * TOPK) {
    const int b = tid >> 4, k = tid & 15;
    const float v = mc[(size_t)b * TT + sel[k]];
    float m = v;
    for (int o = 8; o > 0; o >>= 1) m = fmaxf(m, __shfl_xor(m, o, 16));
    const float e = expf(v - m);
    float ssum = e;
    for (int o = 8; o > 0; o >>= 1) ssum += __shfl_xor(ssum, o, 16);
    wts[tid] = e / ssum;
  }
}

// ---------- K4: out[b,t,:] = sum_k w[b,k] * V[b,(t+d_k)%T,:] ----------
extern "C" __global__ void __launch_bounds__(256)
k4_out(const float* __restrict__ V, const int* __restrict__ delays,
       const float* __restrict__ wts, float* __restrict__ out) {
  __shared__ int   d_s[TOPK];
  __shared__ float w_s[TOPK];
  // XCD-aware swizzle: 8 XCDs, 2 batches per XCD, consecutive t-tiles per XCD
  const int bid = blockIdx.x;               // 8192
  const int xcd = bid & 7;
  const int loc = bid >> 3;                 // 0..1023
  const int b   = 2 * xcd + (loc >> 9);
  const int t0  = (loc & 511) * 8;
  const int tid = threadIdx.x;
  if (tid < TOPK) { d_s[tid] = delays[tid]; w_s[tid] = wts[b * TOPK + tid]; }
  __syncthreads();
  const int rowp = tid >> 7;
  const int e4   = tid & 127;
  const float* Vb = V   + (size_t)b * TT * TE;
  float*       Ob = out + (size_t)b * TT * TE;
  for (int p = 0; p < 4; ++p) {
    const int t = t0 + p * 2 + rowp;
    float4 acc = {0.f, 0.f, 0.f, 0.f};
#pragma unroll
    for (int k = 0; k < TOPK; ++k) {
      const int ts = (t + d_s[k]) & (TT - 1);
      const float4 v = *(const float4*)(Vb + (size_t)ts * TE + e4 * 4);
      const float w = w_s[k];
      acc.x += w * v.x; acc.y += w * v.y; acc.z += w * v.z; acc.w += w * v.w;
    }
    *(float4*)(Ob + (size_t)t * TE + e4 * 4) = acc;
  }
}

// ---------- launch ----------
extern "C" void kernel_launch(void* const* d_in, const int* in_sizes, int n_in,
                              void* d_out, int out_size, void* d_ws, size_t ws_size,
                              hipStream_t stream) {
  const float* Q = (const float*)d_in[0];
  const float* K = (const float*)d_in[1];
  const float* V = (const float*)d_in[2];
  float* out = (float*)d_out;

  const size_t KT_FLOATS = (size_t)TB * TE * TT;               // 33,554,432
  const size_t AUX_FLOATS = (size_t)TB * NF * 2 + (size_t)TB * TT + 16 + TB * TOPK;
  const size_t NEED = (KT_FLOATS + AUX_FLOATS) * sizeof(float); // ~134.7 MB

  if (ws_size >= NEED) {
    // fast path: Qt lives in d_out (consumed before K4 overwrites it), Kt + aux in ws
    float* Qt     = out;
    float* Kt     = (float*)d_ws;
    float* S      = Kt + KT_FLOATS;
    float* mc     = S + (size_t)TB * NF * 2;
    int*   delays = (int*)(mc + (size_t)TB * TT);
    float* wts    = (float*)(delays + TOPK);

    hipMemsetAsync(S, 0, (size_t)TB * NF * 2 * sizeof(float), stream);
    k0_transpose<<<TB * 512, 256, 0, stream>>>(Q, K, Qt, Kt);
    k1_fast<<<TB * 16, 512, 0, stream>>>(Qt, Kt, S);
    k2_irfft<<<TB, 512, 0, stream>>>(S, mc);
    k3_select<<<1, 512, 0, stream>>>(mc, delays, wts);
    k4_out<<<TB * (TT / 8), 256, 0, stream>>>(V, delays, wts, out);
  } else {
    // legacy path (known-good): direct strided loads
    float* S      = (float*)d_ws;
    float* mc     = S + (size_t)TB * NF * 2;
    int*   delays = (int*)(mc + (size_t)TB * TT);
    float* wts    = (float*)(delays + TOPK);

    hipMemsetAsync(S, 0, (size_t)TB * NF * 2 * sizeof(float), stream);
    k1_spec<<<TB * 16, 512, 0, stream>>>(Q, K, S);
    k2_irfft<<<TB, 512, 0, stream>>>(S, mc);
    k3_select<<<1, 512, 0, stream>>>(mc, delays, wts);
    k4_out<<<TB * (TT / 8), 256, 0, stream>>>(V, delays, wts, out);
  }
}